// Round 1
// baseline (276.586 us; speedup 1.0000x reference)
//
#include <hip/hip_runtime.h>
#include <cmath>

#define CHUNK   256
#define WARM    32
#define T_LEN   480000
#define BATCH   64
#define CPR     (T_LEN / CHUNK)      /* 1875 chunks per row */
#define NTHREADS (BATCH * CPR)       /* 120000 */

// One recurrence step: yn = B0*xn + B1*x1 + B2*x2 - A1*y1 - A2*y2
#define STEP(XN, YN)                                            \
    {                                                           \
        float u_ = fmaf(B0, (XN), fmaf(B1, x1, B2 * x2));       \
        (YN) = fmaf(-A1, y1, fmaf(-A2, y2, u_));                \
        x2 = x1; x1 = (XN); y2 = y1; y1 = (YN);                 \
    }

__global__ __launch_bounds__(256) void allpass_kernel(
    const float* __restrict__ x, float* __restrict__ y,
    float B0, float B1, float B2, float A1, float A2)
{
    int g = blockIdx.x * 256 + threadIdx.x;
    if (g >= NTHREADS) return;
    int b = g / CPR;
    int c = g - b * CPR;
    const float* __restrict__ xr = x + (size_t)b * T_LEN;
    float* __restrict__ yr = y + (size_t)b * T_LEN;
    const int start = c * CHUNK;

    float x1 = 0.f, x2 = 0.f, y1 = 0.f, y2 = 0.f;

    // Warm-up: run the recurrence over [start-WARM, start) with zero initial
    // state. Pole radius ~0.414 -> state error ~0.414^32 ~ 6e-13 by `start`.
    // Chunk 0 starts at t=0 where zero state is exact.
    if (c > 0) {
        const float4* xw = (const float4*)(xr + start - WARM);
        #pragma unroll
        for (int i = 0; i < WARM / 4; ++i) {
            float4 xv = xw[i];
            float t;
            STEP(xv.x, t); STEP(xv.y, t); STEP(xv.z, t); STEP(xv.w, t);
        }
    }

    // Main: compute and store [start, start+CHUNK)
    const float4* xm = (const float4*)(xr + start);
    float4*       ym = (float4*)(yr + start);
    #pragma unroll 4
    for (int i = 0; i < CHUNK / 4; ++i) {
        float4 xv = xm[i];
        float4 yv;
        STEP(xv.x, yv.x);
        STEP(xv.y, yv.y);
        STEP(xv.z, yv.z);
        STEP(xv.w, yv.w);
        ym[i] = yv;
    }
}

extern "C" void kernel_launch(void* const* d_in, const int* in_sizes, int n_in,
                              void* d_out, int out_size, void* d_ws, size_t ws_size,
                              hipStream_t stream) {
    const float* x = (const float*)d_in[0];
    float* y = (float*)d_out;

    // Allpass biquad coefficients, computed in double to match numpy, then
    // cast to float32 (torchaudio allpass_biquad semantics, normalized by a0).
    const double sample_rate = 16000.0, central_freq = 4000.0, Q = 0.707;
    const double w0 = 2.0 * M_PI * central_freq / sample_rate;
    const double alpha = sin(w0) / (2.0 * Q);
    const double cw = cos(w0);
    const double a0 = 1.0 + alpha;
    const float B0 = (float)((1.0 - alpha) / a0);
    const float B1 = (float)((-2.0 * cw) / a0);
    const float B2 = (float)((1.0 + alpha) / a0);
    const float A1 = (float)((-2.0 * cw) / a0);
    const float A2 = (float)((1.0 - alpha) / a0);

    const int blocks = (NTHREADS + 255) / 256;
    allpass_kernel<<<blocks, 256, 0, stream>>>(x, y, B0, B1, B2, A1, A2);
}

// Round 2
// 217.826 us; speedup vs baseline: 1.2698x; 1.2698x over previous
//
#include <hip/hip_runtime.h>
#include <cmath>

#define T_LEN   480000
#define BATCH   64
#define CHUNK   32                       /* samples per thread */
#define TPB     256
#define TS      (TPB * CHUNK)            /* 8192 samples per tile */
#define TPR     ((T_LEN + TS - 1) / TS)  /* 59 tiles per row */
#define NLOAD_MAX (TS + CHUNK)
/* skew: +1 float per 32 -> compute-phase stride-33 => 2-way bank alias (free) */
#define LDS_SLOTS (NLOAD_MAX + (NLOAD_MAX >> 5))  /* 8481 floats = 33.9 KB */

__device__ __forceinline__ int slot(int i) { return i + (i >> 5); }

__global__ __launch_bounds__(TPB) void allpass_kernel(
    const float* __restrict__ x, float* __restrict__ y,
    float B0, float B1, float B2, float A1, float A2)
{
    __shared__ float lds[LDS_SLOTS];
    const int tid  = threadIdx.x;
    const int row  = blockIdx.x / TPR;
    const int tb   = blockIdx.x % TPR;
    const int sbase = tb * TS;
    const int ns   = min(TS, T_LEN - sbase);      /* 8192, last tile 4864 */
    const float* __restrict__ xr = x + (size_t)row * T_LEN + sbase;
    float* __restrict__ yr       = y + (size_t)row * T_LEN + sbase;

    /* ---- coalesced load of [sbase-32, sbase+ns) into skewed LDS ---- */
    const int nload = ns + CHUNK;                 /* multiple of 4 */
    for (int i4 = tid * 4; i4 < nload; i4 += TPB * 4) {
        float4 v;
        if (tb == 0 && i4 < CHUNK) {
            v = make_float4(0.f, 0.f, 0.f, 0.f);  /* zero state before t=0 */
        } else {
            v = *(const float4*)(xr - CHUNK + i4);
        }
        lds[slot(i4 + 0)] = v.x;
        lds[slot(i4 + 1)] = v.y;
        lds[slot(i4 + 2)] = v.z;
        lds[slot(i4 + 3)] = v.w;
    }
    __syncthreads();

    /* ---- per-thread recurrence: 32 warm-up + 32 real steps ---- */
    float yv[CHUNK];
    const int ls = tid * CHUNK;                   /* local sample start */
    const bool active = (ls < ns);
    if (active) {
        float x1 = 0.f, x2 = 0.f, y1 = 0.f, y2 = 0.f;
        /* warm region: slot(ls+t) = tid*33 + t, contiguous */
        const int base = slot(ls);
        #pragma unroll
        for (int t = 0; t < CHUNK; ++t) {
            float xn = lds[base + t];
            float u  = fmaf(B0, xn, fmaf(B1, x1, B2 * x2));
            float yn = fmaf(-A1, y1, fmaf(-A2, y2, u));
            x2 = x1; x1 = xn; y2 = y1; y1 = yn;
        }
        const int base2 = slot(ls + CHUNK);       /* = base + 33, contiguous */
        #pragma unroll
        for (int t = 0; t < CHUNK; ++t) {
            float xn = lds[base2 + t];
            float u  = fmaf(B0, xn, fmaf(B1, x1, B2 * x2));
            float yn = fmaf(-A1, y1, fmaf(-A2, y2, u));
            yv[t] = yn;
            x2 = x1; x1 = xn; y2 = y1; y1 = yn;
        }
    }
    __syncthreads();                              /* all LDS reads done */

    /* ---- stage y through LDS for coalesced stores ---- */
    if (active) {
        const int base = slot(ls);
        #pragma unroll
        for (int t = 0; t < CHUNK; ++t) lds[base + t] = yv[t];
    }
    __syncthreads();

    for (int i4 = tid * 4; i4 < ns; i4 += TPB * 4) {
        float4 v;
        v.x = lds[slot(i4 + 0)];
        v.y = lds[slot(i4 + 1)];
        v.z = lds[slot(i4 + 2)];
        v.w = lds[slot(i4 + 3)];
        *(float4*)(yr + i4) = v;
    }
}

extern "C" void kernel_launch(void* const* d_in, const int* in_sizes, int n_in,
                              void* d_out, int out_size, void* d_ws, size_t ws_size,
                              hipStream_t stream) {
    const float* x = (const float*)d_in[0];
    float* y = (float*)d_out;

    const double sample_rate = 16000.0, central_freq = 4000.0, Q = 0.707;
    const double w0 = 2.0 * M_PI * central_freq / sample_rate;
    const double alpha = sin(w0) / (2.0 * Q);
    const double cw = cos(w0);
    const double a0 = 1.0 + alpha;
    const float B0 = (float)((1.0 - alpha) / a0);
    const float B1 = (float)((-2.0 * cw) / a0);
    const float B2 = (float)((1.0 + alpha) / a0);
    const float A1 = (float)((-2.0 * cw) / a0);
    const float A2 = (float)((1.0 - alpha) / a0);

    const int blocks = BATCH * TPR;   /* 3776 */
    allpass_kernel<<<blocks, TPB, 0, stream>>>(x, y, B0, B1, B2, A1, A2);
}